// Round 10
// baseline (1963.494 us; speedup 1.0000x reference)
//
#include <hip/hip_runtime.h>
#include <math.h>

// NeuroSAT, MI355X. Round 10: two kernel launches per step (no persistent
// kernel, no software barriers).
//  - r4/r5/r7/r9 all plateaued at ~1850us: the software grid barrier costs
//    ~40-55us/step (serialized per-block release writebacks + LLC spin +
//    straggler coupling) vs ~22us/step of VALU work. Kernel boundaries get
//    the same coherence from HW barrier packets, per-XCD-parallel (r1 showed
//    graph-replayed dispatches pipeline with negligible gaps).
//  - Step s: clause_step_k(out_cur, ch_prev -> ch_cur) then
//            lit_step_k(out_cur, ch_cur -> out_nxt). out/ch double-buffered
//    (unit-half blocks share rows: in-place would race within a launch).
//    cc/lc persist in global (in-place safe: each piece owned by one thread).
//  - Block internals and FMA order identical to r9 -> absmax ~0.01367.

#define NV2_   800
#define NC_    440
#define KK_    12
#define NPG_   1240
#define NLIT_  12800
#define NCLS_  7040
#define NE_    84480
#define NN_    19840
#define STEPS_ 23

__device__ __forceinline__ float sigmf(float x) { return 1.0f / (1.0f + __expf(-x)); }
__device__ __forceinline__ float tanhf_(float x) { return 1.0f - 2.0f / (__expf(2.0f * x) + 1.0f); }

// ---------------- setup kernels (unchanged) ----------------

__global__ __launch_bounds__(256) void collapse_k(
    const float* lm1, const float* lm1b, const float* lm2, const float* lm2b, const float* lm3, const float* lm3b,
    const float* cm1, const float* cm1b, const float* cm2, const float* cm2b, const float* cm3, const float* cm3b,
    const float* lv1, const float* lv1b, const float* lv2, const float* lv2b, const float* lv3, const float* lv3b,
    float* Wl, float* bl, float* Wc, float* bc, float* Wv, float* bv)
{
    __shared__ float T[4096];
    __shared__ float ub[64];
    __shared__ float t3[64];
    int r = blockIdx.x, t = threadIdx.x;
    if (r < 2) {
        const float* w1 = r ? cm1 : lm1; const float* b1 = r ? cm1b : lm1b;
        const float* w2 = r ? cm2 : lm2; const float* b2 = r ? cm2b : lm2b;
        const float* w3 = r ? cm3 : lm3; const float* b3 = r ? cm3b : lm3b;
        float* W = r ? Wc : Wl;  float* bb = r ? bc : bl;
        for (int idx = t; idx < 4096; idx += 256) {
            int i = idx >> 6, j = idx & 63;
            float s = 0.f;
            for (int k = 0; k < 64; ++k) s += w1[i * 64 + k] * w2[k * 64 + j];
            T[idx] = s;
        }
        if (t < 64) {
            float s = 0.f;
            for (int k = 0; k < 64; ++k) s += b1[k] * w2[k * 64 + t];
            ub[t] = s + b2[t];
        }
        __syncthreads();
        for (int idx = t; idx < 4096; idx += 256) {
            int i = idx >> 6, j = idx & 63;
            float s = 0.f;
            for (int k = 0; k < 64; ++k) s += T[i * 64 + k] * w3[k * 64 + j];
            W[idx] = s;
        }
        if (t < 64) {
            float s = 0.f;
            for (int k = 0; k < 64; ++k) s += ub[k] * w3[k * 64 + t];
            bb[t] = s + b3[t];
        }
    } else {
        if (t < 64) {
            float s = 0.f;
            for (int j = 0; j < 64; ++j) s += lv2[t * 64 + j] * lv3[j];
            t3[t] = s;
            float s2 = 0.f;
            for (int k = 0; k < 64; ++k) s2 += lv1b[k] * lv2[k * 64 + t];
            ub[t] = s2 + lv2b[t];
        }
        __syncthreads();
        if (t < 64) {
            float s = 0.f;
            for (int k = 0; k < 64; ++k) s += lv1[t * 64 + k] * t3[k];
            Wv[t] = s;
        }
        if (t == 0) {
            float s = 0.f;
            for (int j = 0; j < 64; ++j) s += ub[j] * lv3[j];
            bv[0] = s + lv3b[0];
        }
    }
}

__global__ __launch_bounds__(256) void fold_k(
    const float* Wl, const float* bl, const float* Wc, const float* bc,
    const float* lwih, const float* lbih, const float* lbhh,
    const float* cwih, const float* cbih, const float* cbhh,
    float* Wfl, float* bfl, float* Bl, float* Wfc, float* Bc)
{
    int j = threadIdx.x;
    if (blockIdx.x == 0) {
        for (int i = 0; i < 64; ++i) {
            float s = 0.f;
            for (int m = 0; m < 64; ++m) s += Wc[i * 64 + m] * lwih[(64 + m) * 256 + j];
            Wfl[i * 256 + j] = s;
        }
        float s = 0.f;
        for (int m = 0; m < 64; ++m) s += bc[m] * lwih[(64 + m) * 256 + j];
        bfl[j] = s;
        Bl[j] = lbih[j] + lbhh[j];
    } else {
        for (int i = 0; i < 64; ++i) {
            float s = 0.f;
            for (int m = 0; m < 64; ++m) s += Wl[i * 64 + m] * cwih[m * 256 + j];
            Wfc[i * 256 + j] = s;
        }
        float s = 0.f;
        for (int m = 0; m < 64; ++m) s += bl[m] * cwih[m * 256 + j];
        Bc[j] = cbih[j] + cbhh[j] + 13.f * s;
    }
}

__global__ __launch_bounds__(256) void init_k(
    const float* x, const float* liw, const float* lib, const float* ciw, const float* cib,
    float* out0, float* outc)
{
    int t = blockIdx.x * 256 + threadIdx.x;
    if (t >= NN_ * 64) return;
    int node = t >> 6, j = t & 63;
    int b = node / NPG_;
    int i = node - b * NPG_;
    float x0 = x[node * 2 + 0], x1 = x[node * 2 + 1];
    if (i < NV2_) {
        int sp = (i < 400) ? 2 * i : 2 * (i - 400) + 1;
        out0[(size_t)(b * NV2_ + sp) * 64 + j] = x0 * liw[j] + x1 * liw[64 + j] + lib[j];
    } else {
        outc[(size_t)(b * NC_ + (i - NV2_)) * 64 + j] = x0 * ciw[j] + x1 * ciw[64 + j] + cib[j];
    }
}

__global__ __launch_bounds__(256) void econv_k(const int* ei, int* llits, int* cnt)
{
    int e = blockIdx.x * 256 + threadIdx.x;
    if (e >= NE_) return;
    int g = ei[e];
    int b = g / NPG_;
    int i = g - b * NPG_;
    int sp = (i < 400) ? 2 * i : 2 * (i - 400) + 1;
    int L = b * NV2_ + sp;
    llits[e] = L;
    atomicAdd(cnt + L, 1);
}

__global__ __launch_bounds__(1024) void scan_k(const int* cnt, int* rowptr, int* cursor)
{
    __shared__ int sums[1024];
    int t = threadIdx.x;
    int i0 = t * 13;
    int i1 = i0 + 13; if (i1 > NLIT_) i1 = NLIT_; if (i0 > NLIT_) i0 = NLIT_;
    int s = 0;
    for (int i = i0; i < i1; ++i) s += cnt[i];
    sums[t] = s;
    __syncthreads();
    for (int off = 1; off < 1024; off <<= 1) {
        int v = (t >= off) ? sums[t - off] : 0;
        __syncthreads();
        sums[t] += v;
        __syncthreads();
    }
    int run = sums[t] - s;
    for (int i = i0; i < i1; ++i) { rowptr[i] = run; cursor[i] = run; run += cnt[i]; }
    if (t == 1023) rowptr[NLIT_] = sums[1023];
}

__global__ __launch_bounds__(256) void fill_k(const int* llits, int* cursor, int* col)
{
    int e = blockIdx.x * 256 + threadIdx.x;
    if (e >= NE_) return;
    int pos = atomicAdd(cursor + llits[e], 1);
    col[pos] = e / KK_;
}

// ---------------- shared device helpers ----------------

// acc[g*4+q] += sum_k row[k] * W[k*WC + g*GS + uc4 + q]   (weights: LDS broadcast)
template<int WC, int GS>
__device__ __forceinline__ void gemm16(const float* __restrict__ row,
                                       const float* __restrict__ W,
                                       int uc4, float* acc)
{
    const float4* p = (const float4*)row;
#pragma unroll 4
    for (int k4 = 0; k4 < 16; ++k4) {
        float4 v = p[k4];
        const float* wk = W + (k4 * 4) * WC + uc4;
#pragma unroll
        for (int e = 0; e < 4; ++e) {
            float u = (e == 0) ? v.x : (e == 1) ? v.y : (e == 2) ? v.z : v.w;
            const float* wb = wk + e * WC;
#pragma unroll
            for (int g = 0; g < 4; ++g) {
                float4 w = *(const float4*)(wb + g * GS);
                acc[g * 4 + 0] = fmaf(u, w.x, acc[g * 4 + 0]);
                acc[g * 4 + 1] = fmaf(u, w.y, acc[g * 4 + 1]);
                acc[g * 4 + 2] = fmaf(u, w.z, acc[g * 4 + 2]);
                acc[g * 4 + 3] = fmaf(u, w.w, acc[g * 4 + 3]);
            }
        }
    }
}

__device__ __forceinline__ void cell4(const float* acc, float* c, float* h)
{
#pragma unroll
    for (int q = 0; q < 4; ++q) {
        float iv = sigmf(acc[q]);
        float fv = sigmf(acc[4 + q]);
        float gv = tanhf_(acc[8 + q]);
        float ov = sigmf(acc[12 + q]);
        float c2 = fv * c[q] + iv * gv;
        c[q] = c2;
        h[q] = ov * tanhf_(c2);
    }
}

// ---------------- per-step kernels ----------------

// Clause phase: 110 blocks = 55 rowgroups x 2 unit-halves, 128 rows each.
// reads out_cur (gather), ch_prev, ccg; writes ch_cur, ccg.
__global__ __launch_bounds__(1024) void clause_step_k(
    const float* __restrict__ out_cur, const float* __restrict__ outc0,
    float* __restrict__ ch_cur, const float* __restrict__ ch_prev, float* __restrict__ ccg,
    const int* __restrict__ llits,
    const float* __restrict__ Wfc, const float* __restrict__ cwhh, const float* __restrict__ Bc,
    int step)
{
    __shared__ float wfc_s[8192];
    __shared__ float cwhh_s[8192];
    __shared__ float LM[128 * 68];
    __shared__ float CH[128 * 68];
    const int tid = threadIdx.x;
    const int lane = tid & 63;
    const int wv = tid >> 6;
    const int rowgrp = blockIdx.x >> 1;
    const int half = blockIdx.x & 1;
    const int U0 = half * 32;
    const int Cb = rowgrp * 128;

    for (int i2 = tid; i2 < 8192; i2 += 1024) {
        int k = i2 >> 7, r = i2 & 127, gg = r >> 5, j = r & 31;
        int src = k * 256 + gg * 64 + U0 + j;
        wfc_s[i2]  = Wfc[src];
        cwhh_s[i2] = cwhh[src];
    }

    // gather: lmsg = (step? ch_prev : outc0) + sum of 12 literal outs; CH = ch_prev
    for (int s8 = 0; s8 < 8; ++s8) {
        int srow = wv * 8 + s8;
        int c = Cb + srow;
        float v;
        if (step) {
            float ch0 = ch_prev[(size_t)c * 64 + lane];
            CH[srow * 68 + lane] = ch0;
            v = ch0;
        } else {
            v = outc0[(size_t)c * 64 + lane];
        }
        const int* lp = llits + c * KK_;
        float t0 = out_cur[(size_t)lp[0] * 64 + lane];
        float t1 = out_cur[(size_t)lp[1] * 64 + lane];
        float t2 = out_cur[(size_t)lp[2] * 64 + lane];
        float t3 = out_cur[(size_t)lp[3] * 64 + lane];
        float t4 = out_cur[(size_t)lp[4] * 64 + lane];
        float t5 = out_cur[(size_t)lp[5] * 64 + lane];
        float t6 = out_cur[(size_t)lp[6] * 64 + lane];
        float t7 = out_cur[(size_t)lp[7] * 64 + lane];
        float t8 = out_cur[(size_t)lp[8] * 64 + lane];
        float t9 = out_cur[(size_t)lp[9] * 64 + lane];
        float ta = out_cur[(size_t)lp[10] * 64 + lane];
        float tb = out_cur[(size_t)lp[11] * 64 + lane];
        v += t0 + t1 + t2 + t3 + t4 + t5 + t6 + t7 + t8 + t9 + ta + tb;
        LM[srow * 68 + lane] = v;
    }
    __syncthreads();

    const int rh = wv >> 3, uc = wv & 7, uc4 = uc * 4;
    const int lr = rh * 64 + lane;
    const int c = Cb + lr;
    const int unit0 = U0 + uc4;

    float acc[16];
    if (step) {
        float acc2[16];
#pragma unroll
        for (int i = 0; i < 16; ++i) acc2[i] = 0.f;
        gemm16<128, 32>(CH + (size_t)lr * 68, cwhh_s, uc4, acc2);   // ch(s-1) @ whh
#pragma unroll
        for (int g = 0; g < 4; ++g)
#pragma unroll
            for (int q = 0; q < 4; ++q) acc[g * 4 + q] = Bc[g * 64 + unit0 + q] + acc2[g * 4 + q];
    } else {
#pragma unroll
        for (int g = 0; g < 4; ++g)
#pragma unroll
            for (int q = 0; q < 4; ++q) acc[g * 4 + q] = Bc[g * 64 + unit0 + q];
    }
    gemm16<128, 32>(LM + (size_t)lr * 68, wfc_s, uc4, acc);          // folded l_msg

    float cc4[4];
    if (step) {
        float4 cp = *(const float4*)(ccg + (size_t)c * 64 + unit0);
        cc4[0] = cp.x; cc4[1] = cp.y; cc4[2] = cp.z; cc4[3] = cp.w;
    } else {
        cc4[0] = cc4[1] = cc4[2] = cc4[3] = 0.f;
    }
    float h2[4];
    cell4(acc, cc4, h2);
    *(float4*)(ch_cur + (size_t)c * 64 + unit0) = make_float4(h2[0], h2[1], h2[2], h2[3]);
    *(float4*)(ccg + (size_t)c * 64 + unit0) = make_float4(cc4[0], cc4[1], cc4[2], cc4[3]);
}

// Literal phase: 200 blocks = 100 rowgroups x 2 unit-halves, 128 rows each.
// reads out_cur, ch_cur (CSR gather), lcg; writes out_nxt, lcg; vote on last step.
__global__ __launch_bounds__(1024) void lit_step_k(
    const float* __restrict__ out_cur, float* __restrict__ out_nxt,
    const float* __restrict__ chg, float* __restrict__ lcg,
    const int* __restrict__ rowptr, const int* __restrict__ col,
    const float* __restrict__ lwih, const float* __restrict__ lwhh, const float* __restrict__ Wfl,
    const float* __restrict__ bfl, const float* __restrict__ Bl,
    const float* __restrict__ Wv, const float* __restrict__ bv, float* __restrict__ vout,
    int step)
{
    __shared__ float wih_s[8192];
    __shared__ float whh_s[8192];
    __shared__ float wfl_s[8192];
    __shared__ float buf[128 * 68];
    const int tid = threadIdx.x;
    const int lane = tid & 63;
    const int wv = tid >> 6;
    const int rowgrp = blockIdx.x >> 1;
    const int half = blockIdx.x & 1;
    const int U0 = half * 32;
    const int Lb = rowgrp * 128;

    for (int i2 = tid; i2 < 8192; i2 += 1024) {
        int k = i2 >> 7, r = i2 & 127, gg = r >> 5, j = r & 31;
        int src = k * 256 + gg * 64 + U0 + j;
        wih_s[i2] = lwih[src];
        whh_s[i2] = lwhh[src];
        wfl_s[i2] = Wfl[src];
    }

    // load full out rows (coalesced float4, 2 passes of 64 rows)
    {
        const int trow = tid >> 4;
        const int tc4 = (tid & 15) << 2;
        *(float4*)(buf + trow * 68 + tc4) =
            *(const float4*)(out_cur + (size_t)(Lb + trow) * 64 + tc4);
        *(float4*)(buf + (trow + 64) * 68 + tc4) =
            *(const float4*)(out_cur + (size_t)(Lb + trow + 64) * 64 + tc4);
    }
    __syncthreads();

    const int rh = wv >> 3, uc = wv & 7, uc4 = uc * 4;
    const int lr = rh * 64 + lane;
    const int R = Lb + lr;
    const int unit0 = U0 + uc4;
    const float degf = 1.f + (float)(rowptr[R + 1] - rowptr[R]);

    float acc[16];
#pragma unroll
    for (int g = 0; g < 4; ++g)
#pragma unroll
        for (int q = 0; q < 4; ++q)
            acc[g * 4 + q] = Bl[g * 64 + unit0 + q] + degf * bfl[g * 64 + unit0 + q];

    gemm16<128, 32>(buf + (size_t)(lr ^ 1) * 68, wih_s, uc4, acc);     // out[flip] @ wih_top
    if (step) gemm16<128, 32>(buf + (size_t)lr * 68, whh_s, uc4, acc); // lh @ whh
    __syncthreads();   // all gemm reads of buf done before gather overwrites

    // CSR gather: c_msg raw = out[l] + sum chg[cols]
    for (int s8 = 0; s8 < 8; ++s8) {
        int srow = wv * 8 + s8;
        int l = Lb + srow;
        int e = rowptr[l], eE = rowptr[l + 1];
        float v = buf[srow * 68 + lane];
        for (; e + 8 <= eE; e += 8) {
            float t0 = chg[(size_t)col[e    ] * 64 + lane];
            float t1 = chg[(size_t)col[e + 1] * 64 + lane];
            float t2 = chg[(size_t)col[e + 2] * 64 + lane];
            float t3 = chg[(size_t)col[e + 3] * 64 + lane];
            float t4 = chg[(size_t)col[e + 4] * 64 + lane];
            float t5 = chg[(size_t)col[e + 5] * 64 + lane];
            float t6 = chg[(size_t)col[e + 6] * 64 + lane];
            float t7 = chg[(size_t)col[e + 7] * 64 + lane];
            v += ((t0 + t1) + (t2 + t3)) + ((t4 + t5) + (t6 + t7));
        }
        for (; e + 4 <= eE; e += 4) {
            float t0 = chg[(size_t)col[e    ] * 64 + lane];
            float t1 = chg[(size_t)col[e + 1] * 64 + lane];
            float t2 = chg[(size_t)col[e + 2] * 64 + lane];
            float t3 = chg[(size_t)col[e + 3] * 64 + lane];
            v += t0 + t1 + t2 + t3;
        }
        for (; e < eE; ++e) v += chg[(size_t)col[e] * 64 + lane];
        buf[srow * 68 + lane] = v;
    }
    __syncthreads();
    gemm16<128, 32>(buf + (size_t)lr * 68, wfl_s, uc4, acc);

    float lc4[4];
    if (step) {
        float4 cp = *(const float4*)(lcg + (size_t)R * 64 + unit0);
        lc4[0] = cp.x; lc4[1] = cp.y; lc4[2] = cp.z; lc4[3] = cp.w;
    } else {
        lc4[0] = lc4[1] = lc4[2] = lc4[3] = 0.f;
    }
    float h2[4];
    cell4(acc, lc4, h2);
    *(float4*)(out_nxt + (size_t)R * 64 + unit0) = make_float4(h2[0], h2[1], h2[2], h2[3]);
    *(float4*)(lcg + (size_t)R * 64 + unit0) = make_float4(lc4[0], lc4[1], lc4[2], lc4[3]);

    if (step == STEPS_ - 1) {
        // vote epilogue: reduce h2 . Wv across the 8 unit-chunk waves
        float p = h2[0] * Wv[unit0] + h2[1] * Wv[unit0 + 1]
                + h2[2] * Wv[unit0 + 2] + h2[3] * Wv[unit0 + 3];
        __syncthreads();
        buf[lr * 8 + uc] = p;
        __syncthreads();
        if (uc == 0) {
            float v = (half == 0) ? bv[0] : 0.f;
#pragma unroll
            for (int w = 0; w < 8; ++w) v += buf[lr * 8 + w];
            int b = R / NV2_;
            int pos = R - b * NV2_;
            int pi = (pos >> 1) + (pos & 1) * 400;   // undo pair-interleave
            atomicAdd(vout + b * NPG_ + pi, v);
        }
    }
}

// ---------------- host ----------------

extern "C" void kernel_launch(void* const* d_in, const int* in_sizes, int n_in,
                              void* d_out, int out_size, void* d_ws, size_t ws_size,
                              hipStream_t stream)
{
    (void)in_sizes; (void)n_in; (void)out_size; (void)ws_size;
    const float* x    = (const float*)d_in[0];
    const int*   ei   = (const int*)d_in[2];
    const float* liw  = (const float*)d_in[4];
    const float* lib  = (const float*)d_in[5];
    const float* ciw  = (const float*)d_in[6];
    const float* cib  = (const float*)d_in[7];
    const float* lm1  = (const float*)d_in[8];
    const float* lm1b = (const float*)d_in[9];
    const float* lm2  = (const float*)d_in[10];
    const float* lm2b = (const float*)d_in[11];
    const float* lm3  = (const float*)d_in[12];
    const float* lm3b = (const float*)d_in[13];
    const float* cm1  = (const float*)d_in[14];
    const float* cm1b = (const float*)d_in[15];
    const float* cm2  = (const float*)d_in[16];
    const float* cm2b = (const float*)d_in[17];
    const float* cm3  = (const float*)d_in[18];
    const float* cm3b = (const float*)d_in[19];
    const float* lu_wih = (const float*)d_in[20];
    const float* lu_whh = (const float*)d_in[21];
    const float* lu_bih = (const float*)d_in[22];
    const float* lu_bhh = (const float*)d_in[23];
    const float* cu_wih = (const float*)d_in[24];
    const float* cu_whh = (const float*)d_in[25];
    const float* cu_bih = (const float*)d_in[26];
    const float* cu_bhh = (const float*)d_in[27];
    const float* lv1  = (const float*)d_in[28];
    const float* lv1b = (const float*)d_in[29];
    const float* lv2  = (const float*)d_in[30];
    const float* lv2b = (const float*)d_in[31];
    const float* lv3  = (const float*)d_in[32];
    const float* lv3b = (const float*)d_in[33];

    float* F = (float*)d_ws;
    size_t o = 0;
    auto A = [&](size_t n) { float* p = F + o; o += n; return p; };
    float* outA  = A((size_t)NLIT_ * 64);
    float* outB  = A((size_t)NLIT_ * 64);
    float* outc0 = A((size_t)NCLS_ * 64);
    float* chA   = A((size_t)NCLS_ * 64);
    float* chB   = A((size_t)NCLS_ * 64);
    float* ccg   = A((size_t)NCLS_ * 64);
    float* lcg   = A((size_t)NLIT_ * 64);
    float* Wl    = A(4096);
    float* Wc    = A(4096);
    float* bl    = A(64);
    float* bc    = A(64);
    float* Wv    = A(64);
    float* bv    = A(16);
    float* Wfl   = A(64 * 256);
    float* bfl   = A(256);
    float* Bl    = A(256);
    float* Wfc   = A(64 * 256);
    float* Bc    = A(256);
    int* I = (int*)(F + o);
    int* llits  = I; I += NE_;
    int* rowptr = I; I += 12804;
    int* cursor = I; I += NLIT_;
    int* colA_  = I; I += NE_;
    int* cnt    = I; I += NLIT_;

    hipMemsetAsync(cnt, 0, NLIT_ * sizeof(int), stream);
    hipMemsetAsync(d_out, 0, (size_t)NN_ * sizeof(float), stream);

    collapse_k<<<3, 256, 0, stream>>>(lm1, lm1b, lm2, lm2b, lm3, lm3b,
                                      cm1, cm1b, cm2, cm2b, cm3, cm3b,
                                      lv1, lv1b, lv2, lv2b, lv3, lv3b,
                                      Wl, bl, Wc, bc, Wv, bv);
    fold_k<<<2, 256, 0, stream>>>(Wl, bl, Wc, bc,
                                  lu_wih, lu_bih, lu_bhh,
                                  cu_wih, cu_bih, cu_bhh,
                                  Wfl, bfl, Bl, Wfc, Bc);
    init_k<<<(NN_ * 64 + 255) / 256, 256, 0, stream>>>(x, liw, lib, ciw, cib, outA, outc0);
    econv_k<<<NE_ / 256, 256, 0, stream>>>(ei, llits, cnt);
    scan_k<<<1, 1024, 0, stream>>>(cnt, rowptr, cursor);
    fill_k<<<NE_ / 256, 256, 0, stream>>>(llits, cursor, colA_);

    for (int s = 0; s < STEPS_; ++s) {
        const float* oc = (s & 1) ? outB : outA;
        float*       on = (s & 1) ? outA : outB;
        float*       chc = (s & 1) ? chA : chB;   // ch_cur
        const float* chp = (s & 1) ? chB : chA;   // ch_prev (unused at s=0)
        clause_step_k<<<110, 1024, 0, stream>>>(oc, outc0, chc, chp, ccg,
                                                llits, Wfc, cu_whh, Bc, s);
        lit_step_k<<<200, 1024, 0, stream>>>(oc, on, chc, lcg, rowptr, colA_,
                                             lu_wih, lu_whh, Wfl, bfl, Bl,
                                             Wv, bv, (float*)d_out, s);
    }
}